// Round 1
// baseline (108.235 us; speedup 1.0000x reference)
//
#include <hip/hip_runtime.h>
#include <math.h>

#define NG      1024
#define IMG_H   128
#define IMG_W   128
#define NPIX    (IMG_H * IMG_W)
#define MIN_A   (1.0f / 255.0f)

// ---------------------------------------------------------------------------
// Kernel 1: project gaussians, build conics, stable-sort by z (rank counting),
// scatter sorted per-gaussian data into workspace.
// One block, 1024 threads (= NG).
// ---------------------------------------------------------------------------
__global__ __launch_bounds__(NG) void gs_preprocess_sort(
    const float* __restrict__ pos,   // (NG,3)
    const float* __restrict__ cov,   // (NG,3,3)
    const float* __restrict__ col,   // (NG,3)
    const float* __restrict__ opa,   // (NG,)
    const float* __restrict__ cm,    // (4,4) row-major
    float4* __restrict__ g0,         // sorted: {mx, my, conicA, conicB}
    float4* __restrict__ g1,         // sorted: {conicC, op_eff, colR, colG}
    float*  __restrict__ g2)         // sorted: colB
{
    __shared__ float zsh[NG];
    const int i = threadIdx.x;

    const float R00 = cm[0], R01 = cm[1], R02 = cm[2],  T0 = cm[3];
    const float R10 = cm[4], R11 = cm[5], R12 = cm[6],  T1 = cm[7];
    const float R20 = cm[8], R21 = cm[9], R22 = cm[10], T2 = cm[11];

    const float p0 = pos[3*i], p1 = pos[3*i+1], p2 = pos[3*i+2];
    const float x = R00*p0 + R01*p1 + R02*p2 + T0;
    const float y = R10*p0 + R11*p1 + R12*p2 + T1;
    const float z = R20*p0 + R21*p1 + R22*p2 + T2;

    const float focal = 110.85125168440814f;   // 0.5*128/tan(pi/6) = 64*sqrt(3)
    const float zc = fmaxf(z, 1e-6f);
    const float mx = focal * x / zc + 0.5f * IMG_W;
    const float my = focal * y / zc + 0.5f * IMG_H;

    // symmetrized covariance
    const float c00 = cov[9*i+0], c01 = cov[9*i+1], c02 = cov[9*i+2];
    const float c10 = cov[9*i+3], c11 = cov[9*i+4], c12 = cov[9*i+5];
    const float c20 = cov[9*i+6], c21 = cov[9*i+7], c22 = cov[9*i+8];
    const float s00 = c00, s01 = 0.5f*(c01+c10), s02 = 0.5f*(c02+c20);
    const float s11 = c11, s12 = 0.5f*(c12+c21), s22 = c22;

    // RS = R * S
    const float RS00 = R00*s00 + R01*s01 + R02*s02;
    const float RS01 = R00*s01 + R01*s11 + R02*s12;
    const float RS02 = R00*s02 + R01*s12 + R02*s22;
    const float RS10 = R10*s00 + R11*s01 + R12*s02;
    const float RS11 = R10*s01 + R11*s11 + R12*s12;
    const float RS12 = R10*s02 + R11*s12 + R12*s22;
    const float RS20 = R20*s00 + R21*s01 + R22*s02;
    const float RS21 = R20*s01 + R21*s11 + R22*s12;
    const float RS22 = R20*s02 + R21*s12 + R22*s22;
    // CC = RS * R^T   (camera-space covariance)
    const float CC00 = RS00*R00 + RS01*R01 + RS02*R02;
    const float CC01 = RS00*R10 + RS01*R11 + RS02*R12;
    const float CC02 = RS00*R20 + RS01*R21 + RS02*R22;
    const float CC11 = RS10*R10 + RS11*R11 + RS12*R12;
    const float CC12 = RS10*R20 + RS11*R21 + RS12*R22;
    const float CC20 = RS20*R00 + RS21*R01 + RS22*R02;
    const float CC21 = RS20*R10 + RS21*R11 + RS22*R12;
    const float CC22 = RS20*R20 + RS21*R21 + RS22*R22;

    // Jacobian rows: J0 = [f/zc, 0, -f*x/zc^2], J1 = [0, f/zc, -f*y/zc^2]
    const float j00 = focal / zc, j02 = -focal * x / (zc*zc);
    const float j11 = focal / zc, j12 = -focal * y / (zc*zc);

    // v0 = CC @ J0^T (components 0 and 2), v1 = CC @ J1^T
    const float v00 = CC00*j00 + CC02*j02;
    const float v02 = CC20*j00 + CC22*j02;
    const float v10 = CC01*j11 + CC02*j12;
    const float v11 = CC11*j11 + CC12*j12;
    const float v12 = CC21*j11 + CC22*j12;

    const float a  = j00*v00 + j02*v02 + 0.3f;
    const float b  = j00*v10 + j02*v12;
    const float cQ = j11*v11 + j12*v12 + 0.3f;

    const float det = a*cQ - b*b;
    const float det_safe = (det > 0.f) ? det : 1.f;
    const float conA =  cQ / det_safe;
    const float conB = -b  / det_safe;
    const float conC =  a  / det_safe;

    const bool  valid  = (z > 0.2f) && (det > 0.f);
    const float op_eff = valid ? opa[i] : 0.f;   // folds validity into alpha gate

    // stable rank sort by z (ties broken by original index, = jnp.argsort)
    zsh[i] = z;
    __syncthreads();
    int rank = 0;
    for (int j = 0; j < NG; ++j) {
        const float zj = zsh[j];
        rank += (zj < z || (zj == z && j < i)) ? 1 : 0;
    }

    g0[rank] = make_float4(mx, my, conA, conB);
    g1[rank] = make_float4(conC, op_eff, col[3*i], col[3*i+1]);
    g2[rank] = col[3*i+2];
}

// ---------------------------------------------------------------------------
// Kernel 2: per-pixel front-to-back alpha compositing over sorted gaussians.
// 64 blocks x 256 threads; gaussian data staged in LDS (36 KB), inner-loop
// reads are wave-uniform -> LDS broadcast (no bank conflicts).
// ---------------------------------------------------------------------------
__global__ __launch_bounds__(256) void gs_raster(
    const float4* __restrict__ g0,
    const float4* __restrict__ g1,
    const float*  __restrict__ g2,
    float* __restrict__ out)
{
    __shared__ float4 s0[NG];
    __shared__ float4 s1[NG];
    __shared__ float  s2[NG];

    const int tid = threadIdx.x;
    for (int j = tid; j < NG; j += 256) {
        s0[j] = g0[j];
        s1[j] = g1[j];
        s2[j] = g2[j];
    }
    __syncthreads();

    const int p = blockIdx.x * 256 + tid;
    const float pxf = (float)(p & (IMG_W - 1)) + 0.5f;
    const float pyf = (float)(p >> 7) + 0.5f;

    float T = 1.f, cr = 0.f, cg = 0.f, cb = 0.f;

    #pragma unroll 4
    for (int i = 0; i < NG; ++i) {
        const float4 A = s0[i];            // mx, my, conA, conB
        const float4 B = s1[i];            // conC, op, colR, colG
        const float dx = pxf - A.x;
        const float dy = pyf - A.y;
        float power = -0.5f * (A.z*dx*dx + B.x*dy*dy) - A.w*dx*dy;
        power = fminf(power, 0.f);
        const float G = __expf(power);
        float alpha = fminf(B.y * G, 0.99f);
        alpha = (alpha >= MIN_A) ? alpha : 0.f;
        const float wT = alpha * T;
        cr += wT * B.z;
        cg += wT * B.w;
        cb += wT * s2[i];
        T *= (1.f - alpha);
    }

    float* o = out + 3 * p;
    o[0] = cr; o[1] = cg; o[2] = cb;
}

// ---------------------------------------------------------------------------
extern "C" void kernel_launch(void* const* d_in, const int* in_sizes, int n_in,
                              void* d_out, int out_size, void* d_ws, size_t ws_size,
                              hipStream_t stream) {
    const float* pos = (const float*)d_in[0];
    const float* cov = (const float*)d_in[1];
    const float* col = (const float*)d_in[2];
    const float* opa = (const float*)d_in[3];
    const float* cm  = (const float*)d_in[4];

    float4* g0 = (float4*)d_ws;          // NG float4
    float4* g1 = g0 + NG;                // NG float4
    float*  g2 = (float*)(g1 + NG);      // NG float   (36 KB total)

    gs_preprocess_sort<<<1, NG, 0, stream>>>(pos, cov, col, opa, cm, g0, g1, g2);
    gs_raster<<<NPIX / 256, 256, 0, stream>>>(g0, g1, g2, (float*)d_out);
}

// Round 2
// 50.761 us; speedup vs baseline: 2.1322x; 2.1322x over previous
//
#include <hip/hip_runtime.h>
#include <math.h>

#define NG      1024
#define IMG_H   128
#define IMG_W   128
#define NPIX    (IMG_H * IMG_W)
#define MIN_A   (1.0f / 255.0f)
#define LOG2E   1.4426950408889634f

// Record layout (per gaussian, after preprocess):
//  g0 = {mx, my, a2, b2}     a2 = -0.5*conicA*log2e, b2 = -conicB*log2e
//  g1 = {c2, op_eff, colR, colG}   c2 = -0.5*conicC*log2e
//  g2 = colB
// so  G = exp2( min(a2*dx^2 + c2*dy^2 + b2*dx*dy, 0) )

// ---------------------------------------------------------------------------
// shared projection math
// ---------------------------------------------------------------------------
__device__ inline void project_one(
    int i,
    const float* __restrict__ pos, const float* __restrict__ cov,
    const float* __restrict__ col, const float* __restrict__ opa,
    const float* __restrict__ cm,
    float4& r0, float4& r1, float& r2, float& zret)
{
    const float R00 = cm[0], R01 = cm[1], R02 = cm[2],  T0 = cm[3];
    const float R10 = cm[4], R11 = cm[5], R12 = cm[6],  T1 = cm[7];
    const float R20 = cm[8], R21 = cm[9], R22 = cm[10], T2 = cm[11];

    const float p0 = pos[3*i], p1 = pos[3*i+1], p2 = pos[3*i+2];
    const float x = R00*p0 + R01*p1 + R02*p2 + T0;
    const float y = R10*p0 + R11*p1 + R12*p2 + T1;
    const float z = R20*p0 + R21*p1 + R22*p2 + T2;

    const float focal = 110.85125168440814f;   // 0.5*128/tan(pi/6)
    const float zc = fmaxf(z, 1e-6f);
    const float mx = focal * x / zc + 0.5f * IMG_W;
    const float my = focal * y / zc + 0.5f * IMG_H;

    const float c00 = cov[9*i+0], c01 = cov[9*i+1], c02 = cov[9*i+2];
    const float c10 = cov[9*i+3], c11 = cov[9*i+4], c12 = cov[9*i+5];
    const float c20 = cov[9*i+6], c21 = cov[9*i+7], c22 = cov[9*i+8];
    const float s00 = c00, s01 = 0.5f*(c01+c10), s02 = 0.5f*(c02+c20);
    const float s11 = c11, s12 = 0.5f*(c12+c21), s22 = c22;

    const float RS00 = R00*s00 + R01*s01 + R02*s02;
    const float RS01 = R00*s01 + R01*s11 + R02*s12;
    const float RS02 = R00*s02 + R01*s12 + R02*s22;
    const float RS10 = R10*s00 + R11*s01 + R12*s02;
    const float RS11 = R10*s01 + R11*s11 + R12*s12;
    const float RS12 = R10*s02 + R11*s12 + R12*s22;
    const float RS20 = R20*s00 + R21*s01 + R22*s02;
    const float RS21 = R20*s01 + R21*s11 + R22*s12;
    const float RS22 = R20*s02 + R21*s12 + R22*s22;
    const float CC00 = RS00*R00 + RS01*R01 + RS02*R02;
    const float CC01 = RS00*R10 + RS01*R11 + RS02*R12;
    const float CC02 = RS00*R20 + RS01*R21 + RS02*R22;
    const float CC11 = RS10*R10 + RS11*R11 + RS12*R12;
    const float CC12 = RS10*R20 + RS11*R21 + RS12*R22;
    const float CC20 = RS20*R00 + RS21*R01 + RS22*R02;
    const float CC21 = RS20*R10 + RS21*R11 + RS22*R12;
    const float CC22 = RS20*R20 + RS21*R21 + RS22*R22;

    const float j00 = focal / zc, j02 = -focal * x / (zc*zc);
    const float j11 = focal / zc, j12 = -focal * y / (zc*zc);

    const float v00 = CC00*j00 + CC02*j02;
    const float v02 = CC20*j00 + CC22*j02;
    const float v10 = CC01*j11 + CC02*j12;
    const float v11 = CC11*j11 + CC12*j12;
    const float v12 = CC21*j11 + CC22*j12;

    const float a  = j00*v00 + j02*v02 + 0.3f;
    const float b  = j00*v10 + j02*v12;
    const float cQ = j11*v11 + j12*v12 + 0.3f;

    const float det = a*cQ - b*b;
    const float det_safe = (det > 0.f) ? det : 1.f;
    const float conA =  cQ / det_safe;
    const float conB = -b  / det_safe;
    const float conC =  a  / det_safe;

    const bool  valid  = (z > 0.2f) && (det > 0.f);
    const float op_eff = valid ? opa[i] : 0.f;

    r0 = make_float4(mx, my, -0.5f*conA*LOG2E, -conB*LOG2E);
    r1 = make_float4(-0.5f*conC*LOG2E, op_eff, col[3*i], col[3*i+1]);
    r2 = col[3*i+2];
    zret = z;
}

// ---------------------------------------------------------------------------
// Kernel 1: projection, unsorted records. 4 blocks x 256.
// ---------------------------------------------------------------------------
__global__ __launch_bounds__(256) void gs_project(
    const float* __restrict__ pos, const float* __restrict__ cov,
    const float* __restrict__ col, const float* __restrict__ opa,
    const float* __restrict__ cm,
    float4* __restrict__ u0, float4* __restrict__ u1, float* __restrict__ u2,
    float* __restrict__ zout)
{
    const int i = blockIdx.x * 256 + threadIdx.x;
    float4 r0, r1; float r2, z;
    project_one(i, pos, cov, col, opa, cm, r0, r1, r2, z);
    u0[i] = r0; u1[i] = r1; u2[i] = r2; zout[i] = z;
}

// ---------------------------------------------------------------------------
// Kernel 2: stable rank-sort by z + scatter. 4 blocks x 256, z staged in LDS.
// ---------------------------------------------------------------------------
__global__ __launch_bounds__(256) void gs_sort_scatter(
    const float* __restrict__ z,
    const float4* __restrict__ u0, const float4* __restrict__ u1,
    const float* __restrict__ u2,
    float4* __restrict__ g0, float4* __restrict__ g1, float* __restrict__ g2)
{
    __shared__ float zsh[NG];
    const int tid = threadIdx.x;
    for (int j = tid; j < NG; j += 256) zsh[j] = z[j];
    __syncthreads();

    const int i = blockIdx.x * 256 + tid;
    const float zi = zsh[i];
    int rank = 0;
    #pragma unroll 8
    for (int j = 0; j < NG; ++j) {
        const float zj = zsh[j];
        rank += (zj < zi || (zj == zi && j < i)) ? 1 : 0;
    }
    g0[rank] = u0[i]; g1[rank] = u1[i]; g2[rank] = u2[i];
}

// ---------------------------------------------------------------------------
// Kernel 3: per-(pixel, chunk) partial compositing.
// grid = (NPIX/256, NCHUNK); each block stages its GPC gaussians in LDS.
// ---------------------------------------------------------------------------
template<int GPC>
__global__ __launch_bounds__(256) void gs_raster_partial(
    const float4* __restrict__ g0, const float4* __restrict__ g1,
    const float*  __restrict__ g2, float4* __restrict__ part)
{
    __shared__ float4 s0[GPC];
    __shared__ float4 s1[GPC];
    __shared__ float  s2[GPC];

    const int tid  = threadIdx.x;
    const int k    = blockIdx.y;
    const int base = k * GPC;
    for (int j = tid; j < GPC; j += 256) {
        s0[j] = g0[base + j]; s1[j] = g1[base + j]; s2[j] = g2[base + j];
    }
    __syncthreads();

    const int p = blockIdx.x * 256 + tid;
    const float pxf = (float)(p & (IMG_W - 1)) + 0.5f;
    const float pyf = (float)(p >> 7) + 0.5f;

    float T = 1.f, cr = 0.f, cg = 0.f, cb = 0.f;

    #pragma unroll 4
    for (int i = 0; i < GPC; ++i) {
        const float4 A = s0[i];            // mx, my, a2, b2
        const float4 B = s1[i];            // c2, op, colR, colG
        const float dx = pxf - A.x;
        const float dy = pyf - A.y;
        const float pw = fminf(A.z*dx*dx + B.x*dy*dy + A.w*(dx*dy), 0.f);
        const float G = __builtin_amdgcn_exp2f(pw);
        float alpha = fminf(B.y * G, 0.99f);
        alpha = (alpha >= MIN_A) ? alpha : 0.f;
        const float wT = alpha * T;
        cr = fmaf(wT, B.z, cr);
        cg = fmaf(wT, B.w, cg);
        cb = fmaf(wT, s2[i], cb);
        T *= (1.f - alpha);
    }

    part[k * NPIX + p] = make_float4(cr, cg, cb, T);
}

// Direct variant (fallback when workspace is small): whole range, write out.
template<int GPC>
__global__ __launch_bounds__(256) void gs_raster_direct(
    const float4* __restrict__ g0, const float4* __restrict__ g1,
    const float*  __restrict__ g2, float* __restrict__ out)
{
    __shared__ float4 s0[GPC];
    __shared__ float4 s1[GPC];
    __shared__ float  s2[GPC];

    const int tid = threadIdx.x;
    for (int j = tid; j < GPC; j += 256) {
        s0[j] = g0[j]; s1[j] = g1[j]; s2[j] = g2[j];
    }
    __syncthreads();

    const int p = blockIdx.x * 256 + tid;
    const float pxf = (float)(p & (IMG_W - 1)) + 0.5f;
    const float pyf = (float)(p >> 7) + 0.5f;

    float T = 1.f, cr = 0.f, cg = 0.f, cb = 0.f;
    #pragma unroll 4
    for (int i = 0; i < GPC; ++i) {
        const float4 A = s0[i];
        const float4 B = s1[i];
        const float dx = pxf - A.x;
        const float dy = pyf - A.y;
        const float pw = fminf(A.z*dx*dx + B.x*dy*dy + A.w*(dx*dy), 0.f);
        const float G = __builtin_amdgcn_exp2f(pw);
        float alpha = fminf(B.y * G, 0.99f);
        alpha = (alpha >= MIN_A) ? alpha : 0.f;
        const float wT = alpha * T;
        cr = fmaf(wT, B.z, cr);
        cg = fmaf(wT, B.w, cg);
        cb = fmaf(wT, s2[i], cb);
        T *= (1.f - alpha);
    }
    float* o = out + 3 * p;
    o[0] = cr; o[1] = cg; o[2] = cb;
}

// ---------------------------------------------------------------------------
// Kernel 4: combine chunk partials front-to-back. 64 blocks x 256.
// ---------------------------------------------------------------------------
__global__ __launch_bounds__(256) void gs_combine(
    const float4* __restrict__ part, int nchunk, float* __restrict__ out)
{
    const int p = blockIdx.x * 256 + threadIdx.x;
    float T = 1.f, cr = 0.f, cg = 0.f, cb = 0.f;
    for (int k = 0; k < nchunk; ++k) {
        const float4 v = part[k * NPIX + p];
        cr = fmaf(T, v.x, cr);
        cg = fmaf(T, v.y, cg);
        cb = fmaf(T, v.z, cb);
        T *= v.w;
    }
    float* o = out + 3 * p;
    o[0] = cr; o[1] = cg; o[2] = cb;
}

// ---------------------------------------------------------------------------
extern "C" void kernel_launch(void* const* d_in, const int* in_sizes, int n_in,
                              void* d_out, int out_size, void* d_ws, size_t ws_size,
                              hipStream_t stream) {
    const float* pos = (const float*)d_in[0];
    const float* cov = (const float*)d_in[1];
    const float* col = (const float*)d_in[2];
    const float* opa = (const float*)d_in[3];
    const float* cm  = (const float*)d_in[4];

    char* ws = (char*)d_ws;
    // fixed record area: g0|g1|g2|u0|u1|u2|z  = 77824 B
    float4* g0 = (float4*)(ws);                 // 16384
    float4* g1 = (float4*)(ws + 16384);         // 16384
    float*  g2 = (float*) (ws + 32768);         //  4096
    float4* u0 = (float4*)(ws + 36864);         // 16384
    float4* u1 = (float4*)(ws + 53248);         // 16384
    float*  u2 = (float*) (ws + 69632);         //  4096
    float*  zz = (float*) (ws + 73728);         //  4096
    float4* part = (float4*)(ws + 77824);

    const size_t rec = 77824;
    const size_t per_chunk = (size_t)NPIX * 16;   // 256 KB

    // choose chunk count by available workspace
    int nchunk = 0;
    if      (ws_size >= rec + 16 * per_chunk) nchunk = 16;
    else if (ws_size >= rec +  8 * per_chunk) nchunk = 8;
    else if (ws_size >= rec +  4 * per_chunk) nchunk = 4;
    else if (ws_size >= rec +  2 * per_chunk) nchunk = 2;

    gs_project<<<NG/256, 256, 0, stream>>>(pos, cov, col, opa, cm, u0, u1, u2, zz);
    gs_sort_scatter<<<NG/256, 256, 0, stream>>>(zz, u0, u1, u2, g0, g1, g2);

    float* out = (float*)d_out;
    if (nchunk == 16) {
        gs_raster_partial<NG/16><<<dim3(NPIX/256, 16), 256, 0, stream>>>(g0, g1, g2, part);
        gs_combine<<<NPIX/256, 256, 0, stream>>>(part, 16, out);
    } else if (nchunk == 8) {
        gs_raster_partial<NG/8><<<dim3(NPIX/256, 8), 256, 0, stream>>>(g0, g1, g2, part);
        gs_combine<<<NPIX/256, 256, 0, stream>>>(part, 8, out);
    } else if (nchunk == 4) {
        gs_raster_partial<NG/4><<<dim3(NPIX/256, 4), 256, 0, stream>>>(g0, g1, g2, part);
        gs_combine<<<NPIX/256, 256, 0, stream>>>(part, 4, out);
    } else if (nchunk == 2) {
        gs_raster_partial<NG/2><<<dim3(NPIX/256, 2), 256, 0, stream>>>(g0, g1, g2, part);
        gs_combine<<<NPIX/256, 256, 0, stream>>>(part, 2, out);
    } else {
        gs_raster_direct<NG><<<NPIX/256, 256, 0, stream>>>(g0, g1, g2, out);
    }
}